// Round 1
// baseline (544.163 us; speedup 1.0000x reference)
//
#include <hip/hip_runtime.h>

#define T_TOK 4096
#define HDIM  1024
#define NEXP  8
#define FFDIM 4096
#define NPAIR 8192   // T_TOK * topk

typedef __attribute__((ext_vector_type(8))) short short8;
typedef __attribute__((ext_vector_type(8))) unsigned short ushort8;
typedef __attribute__((ext_vector_type(4))) float f32x4;

__device__ __forceinline__ unsigned short f2bf(float f) {
  unsigned int u = __float_as_uint(f);
  u += 0x7fffu + ((u >> 16) & 1u);   // RNE
  return (unsigned short)(u >> 16);
}

// global -> LDS direct copy, 16B per lane. LDS dest must be wave-uniform base;
// HW writes lane l at base + l*16. (CK-style addrspace casts.)
__device__ __forceinline__ void gload16(const void* g, const void* l) {
  __builtin_amdgcn_global_load_lds(
      (const __attribute__((address_space(1))) unsigned int*)(unsigned long long)g,
      (__attribute__((address_space(3))) unsigned int*)(unsigned int)(unsigned long long)l,
      16, 0, 0);
}

// ---------------- conversions ----------------

__global__ __launch_bounds__(256) void convert_x_kernel(
    const float* __restrict__ in, unsigned short* __restrict__ out) {
  int i = (blockIdx.x * 256 + threadIdx.x) * 8;
  float4 a = *(const float4*)(in + i);
  float4 b = *(const float4*)(in + i + 4);
  ushort8 o;
  o[0] = f2bf(a.x); o[1] = f2bf(a.y); o[2] = f2bf(a.z); o[3] = f2bf(a.w);
  o[4] = f2bf(b.x); o[5] = f2bf(b.y); o[6] = f2bf(b.z); o[7] = f2bf(b.w);
  *(ushort8*)(out + i) = o;
}

// [M][N] fp32 -> [N][M] bf16, per-expert (blockIdx.z), 64x64 tiles
__global__ __launch_bounds__(256) void transpose_bf16_kernel(
    const float* __restrict__ in, unsigned short* __restrict__ out, int M, int N) {
  in  += (size_t)blockIdx.z * M * N;
  out += (size_t)blockIdx.z * M * N;
  __shared__ unsigned short t[64][72];
  int tid = threadIdx.x;
  int r0 = blockIdx.y * 64, c0 = blockIdx.x * 64;
#pragma unroll
  for (int rr = 0; rr < 4; rr++) {
    int row = rr * 16 + (tid >> 4);
    int col = (tid & 15) * 4;
    float4 v = *(const float4*)(in + (size_t)(r0 + row) * N + c0 + col);
    t[col + 0][row] = f2bf(v.x);
    t[col + 1][row] = f2bf(v.y);
    t[col + 2][row] = f2bf(v.z);
    t[col + 3][row] = f2bf(v.w);
  }
  __syncthreads();
#pragma unroll
  for (int rr = 0; rr < 2; rr++) {
    int c = rr * 32 + (tid >> 3);
    int m0 = (tid & 7) * 8;
    ushort8 v = *(const ushort8*)&t[c][m0];
    *(ushort8*)(out + (size_t)(c0 + c) * M + r0 + m0) = v;
  }
}

// ---------------- router ----------------

__global__ __launch_bounds__(256) void router_kernel(
    const float* __restrict__ x, const float* __restrict__ wg,
    int* __restrict__ sel_e, float* __restrict__ sel_w, int* __restrict__ counts) {
  int lane = threadIdx.x & 63;
  int t = blockIdx.x * 4 + (threadIdx.x >> 6);
  const float* xr = x + (size_t)t * HDIM;
  float acc[8] = {0, 0, 0, 0, 0, 0, 0, 0};
  for (int i = 0; i < HDIM / 64; i++) {
    int h = i * 64 + lane;
    float xv = xr[h];
    float4 w0 = *(const float4*)(wg + h * 8);
    float4 w1 = *(const float4*)(wg + h * 8 + 4);
    acc[0] += xv * w0.x; acc[1] += xv * w0.y; acc[2] += xv * w0.z; acc[3] += xv * w0.w;
    acc[4] += xv * w1.x; acc[5] += xv * w1.y; acc[6] += xv * w1.z; acc[7] += xv * w1.w;
  }
#pragma unroll
  for (int off = 32; off > 0; off >>= 1) {
#pragma unroll
    for (int e = 0; e < 8; e++) acc[e] += __shfl_xor(acc[e], off, 64);
  }
  if (lane == 0) {
    int e0 = 0; float b0 = acc[0];
#pragma unroll
    for (int e = 1; e < 8; e++) if (acc[e] > b0) { b0 = acc[e]; e0 = e; }
    int e1 = -1; float b1 = -3.4e38f;
#pragma unroll
    for (int e = 0; e < 8; e++) if (e != e0 && acc[e] > b1) { b1 = acc[e]; e1 = e; }
    float q = expf(b1 - b0);                 // softmax denominator cancels in renorm
    float w0 = 1.0f / (1.0f + q);
    float w1 = q / (1.0f + q);
    sel_e[t * 2] = e0; sel_e[t * 2 + 1] = e1;
    sel_w[t * 2] = w0; sel_w[t * 2 + 1] = w1;
    atomicAdd(&counts[e0], 1);
    atomicAdd(&counts[e1], 1);
  }
}

__global__ void offsets_kernel(const int* __restrict__ counts,
                               int* __restrict__ offsets, int* __restrict__ cursor) {
  if (threadIdx.x == 0 && blockIdx.x == 0) {
    int s = 0;
    for (int e = 0; e < NEXP; e++) { offsets[e] = s; cursor[e] = s; s += counts[e]; }
  }
}

__global__ __launch_bounds__(256) void scatter_kernel(
    const int* __restrict__ sel_e, const float* __restrict__ sel_w,
    int* __restrict__ cursor, int* __restrict__ pair_token, float* __restrict__ pair_w) {
  int t = blockIdx.x * 256 + threadIdx.x;
#pragma unroll
  for (int j = 0; j < 2; j++) {
    int e = sel_e[t * 2 + j];
    int pos = atomicAdd(&cursor[e], 1);
    pair_token[pos] = t;
    pair_w[pos] = sel_w[t * 2 + j];
  }
}

// ---------------- expert GEMMs ----------------
// 128x128 tile, BK=64, 4 waves (2x2), MFMA 16x16x32 bf16, m97-style 2-barrier loop.
// A rows: gathered token rows (GEMM1) or h1 rows (GEMM2). B is pre-transposed [N][K].
template <int KD, bool GATHER, bool SQRELU>
__global__ __launch_bounds__(256) void moe_gemm_kernel(
    const unsigned short* __restrict__ A0, const unsigned short* __restrict__ B0,
    const int* __restrict__ offsets, const int* __restrict__ counts,
    const int* __restrict__ pair_token, const float* __restrict__ pair_w,
    unsigned short* __restrict__ h1out, float* __restrict__ out) {
  constexpr int ND = SQRELU ? FFDIM : HDIM;
  int e = blockIdx.z;
  int segstart = offsets[e];
  int segcnt = counts[e];
  int by = blockIdx.y;
  if (by * 128 >= segcnt) return;
  int bx = blockIdx.x;
  const unsigned short* B = B0 + (size_t)e * ND * KD;

  int tid = threadIdx.x;
  int mbase = tid >> 3;   // row within 32-row group
  int kb = tid & 7;       // 16B block along K

  const unsigned short* aPtr[4];
  const unsigned short* bPtr[4];
#pragma unroll
  for (int r = 0; r < 4; r++) {
    int m = mbase + 32 * r;
    int idx = by * 128 + m;
    if (idx >= segcnt) idx = segcnt - 1;  // clamp pad rows to a valid row
    int p = segstart + idx;
    size_t arow;
    if (GATHER) arow = (size_t)pair_token[p] * KD;
    else        arow = (size_t)p * KD;
    aPtr[r] = A0 + arow + kb * 8;
    bPtr[r] = B + (size_t)(bx * 128 + m) * KD + kb * 8;
  }

  __shared__ unsigned short lds[16384];  // A: bytes [0,16K), B: [16K,32K)
  const char* ldsc = (const char*)lds;
  int ldsAbyte = (tid & 192) * 16;       // wave-uniform

  f32x4 acc[4][4];
#pragma unroll
  for (int i = 0; i < 4; i++)
#pragma unroll
    for (int j = 0; j < 4; j++) acc[i][j] = (f32x4){0.f, 0.f, 0.f, 0.f};

  int lane = tid & 63;
  int wv = tid >> 6;
  int wr = wv >> 1, wc = wv & 1;
  int g = lane >> 4, lr = lane & 15;

  for (int kt = 0; kt < KD / 64; ++kt) {
#pragma unroll
    for (int r = 0; r < 4; r++) gload16(aPtr[r], ldsc + ldsAbyte + r * 4096);
#pragma unroll
    for (int r = 0; r < 4; r++) gload16(bPtr[r], ldsc + 16384 + ldsAbyte + r * 4096);
#pragma unroll
    for (int r = 0; r < 4; r++) { aPtr[r] += 64; bPtr[r] += 64; }
    __syncthreads();  // compiler emits vmcnt(0) drain before barrier

    short8 af[2][4], bfr[2][4];
#pragma unroll
    for (int kk = 0; kk < 2; kk++) {
#pragma unroll
      for (int i = 0; i < 4; i++) {
        int rowa = wr * 64 + i * 16 + lr;
        af[kk][i] = *(const short8*)(ldsc + rowa * 128 + (kk * 4 + g) * 16);
        int rowb = wc * 64 + i * 16 + lr;
        bfr[kk][i] = *(const short8*)(ldsc + 16384 + rowb * 128 + (kk * 4 + g) * 16);
      }
    }
#pragma unroll
    for (int i = 0; i < 4; i++)
#pragma unroll
      for (int j = 0; j < 4; j++) {
        acc[i][j] = __builtin_amdgcn_mfma_f32_16x16x32_bf16(af[0][i], bfr[0][j], acc[i][j], 0, 0, 0);
        acc[i][j] = __builtin_amdgcn_mfma_f32_16x16x32_bf16(af[1][i], bfr[1][j], acc[i][j], 0, 0, 0);
      }
    __syncthreads();
  }

  // epilogue: C/D layout col=lane&15, row=(lane>>4)*4+q (m89-verified)
  if (SQRELU) {
#pragma unroll
    for (int i = 0; i < 4; i++) {
      int mloc = wr * 64 + i * 16 + g * 4;
#pragma unroll
      for (int q = 0; q < 4; q++) {
        int idx = by * 128 + mloc + q;
        if (idx < segcnt) {
          size_t p = (size_t)(segstart + idx);
          size_t rowoff = p * FFDIM + bx * 128 + wc * 64 + lr;
#pragma unroll
          for (int j = 0; j < 4; j++) {
            float v = acc[i][j][q];
            v = v > 0.f ? v * v : 0.f;
            h1out[rowoff + j * 16] = f2bf(v);
          }
        }
      }
    }
  } else {
#pragma unroll
    for (int i = 0; i < 4; i++) {
      int mloc = wr * 64 + i * 16 + g * 4;
#pragma unroll
      for (int q = 0; q < 4; q++) {
        int idx = by * 128 + mloc + q;
        if (idx < segcnt) {
          int p = segstart + idx;
          int tok = pair_token[p];
          float wgt = pair_w[p];
          size_t rowoff = (size_t)tok * HDIM + bx * 128 + wc * 64 + lr;
#pragma unroll
          for (int j = 0; j < 4; j++) {
            atomicAdd(out + rowoff + j * 16, acc[i][j][q] * wgt);
          }
        }
      }
    }
  }
}

// ---------------- launch ----------------

extern "C" void kernel_launch(void* const* d_in, const int* in_sizes, int n_in,
                              void* d_out, int out_size, void* d_ws, size_t ws_size,
                              hipStream_t stream) {
  (void)in_sizes; (void)n_in; (void)out_size; (void)ws_size;
  const float* x     = (const float*)d_in[0];
  const float* Wg    = (const float*)d_in[1];
  const float* Wfc   = (const float*)d_in[2];
  const float* Wproj = (const float*)d_in[3];
  float* out = (float*)d_out;

  char* w = (char*)d_ws;
  size_t o = 0;
  auto take = [&](size_t n) { char* p = w + o; o += (n + 255) & ~(size_t)255; return p; };
  unsigned short* xb     = (unsigned short*)take((size_t)T_TOK * HDIM * 2);
  unsigned short* WfcT   = (unsigned short*)take((size_t)NEXP * FFDIM * HDIM * 2);
  unsigned short* WprojT = (unsigned short*)take((size_t)NEXP * HDIM * FFDIM * 2);
  unsigned short* h1     = (unsigned short*)take((size_t)NPAIR * FFDIM * 2);
  int*   sel_e      = (int*)take(T_TOK * 2 * 4);
  float* sel_w      = (float*)take(T_TOK * 2 * 4);
  int*   pair_token = (int*)take(NPAIR * 4);
  float* pair_w     = (float*)take(NPAIR * 4);
  int*   counts     = (int*)take(3 * 8 * 4);
  int*   offsets    = counts + 8;
  int*   cursor     = counts + 16;

  hipMemsetAsync(out, 0, (size_t)T_TOK * HDIM * 4, stream);
  hipMemsetAsync(counts, 0, 96, stream);

  convert_x_kernel<<<T_TOK * HDIM / (256 * 8), 256, 0, stream>>>(x, xb);
  transpose_bf16_kernel<<<dim3(FFDIM / 64, HDIM / 64, NEXP), 256, 0, stream>>>(Wfc, WfcT, HDIM, FFDIM);
  transpose_bf16_kernel<<<dim3(HDIM / 64, FFDIM / 64, NEXP), 256, 0, stream>>>(Wproj, WprojT, FFDIM, HDIM);
  router_kernel<<<T_TOK / 4, 256, 0, stream>>>(x, Wg, sel_e, sel_w, counts);
  offsets_kernel<<<1, 64, 0, stream>>>(counts, offsets, cursor);
  scatter_kernel<<<T_TOK / 256, 256, 0, stream>>>(sel_e, sel_w, cursor, pair_token, pair_w);

  moe_gemm_kernel<HDIM, true, true>
      <<<dim3(FFDIM / 128, 32, NEXP), 256, 0, stream>>>(xb, WfcT, offsets, counts,
                                                        pair_token, pair_w, h1, nullptr);
  moe_gemm_kernel<FFDIM, false, false>
      <<<dim3(HDIM / 128, 32, NEXP), 256, 0, stream>>>(h1, WprojT, offsets, counts,
                                                       pair_token, pair_w, nullptr, out);
}

// Round 2
// 480.953 us; speedup vs baseline: 1.1314x; 1.1314x over previous
//
#include <hip/hip_runtime.h>

#define T_TOK 4096
#define HDIM  1024
#define NEXP  8
#define FFDIM 4096
#define NPAIR 8192   // T_TOK * topk

typedef __attribute__((ext_vector_type(8))) short short8;
typedef __attribute__((ext_vector_type(8))) unsigned short ushort8;
typedef __attribute__((ext_vector_type(4))) float f32x4;

__device__ __forceinline__ unsigned short f2bf(float f) {
  unsigned int u = __float_as_uint(f);
  u += 0x7fffu + ((u >> 16) & 1u);   // RNE
  return (unsigned short)(u >> 16);
}

// global -> LDS direct copy, 16B per lane. LDS dest is wave-uniform base;
// HW writes lane l at base + l*16.
__device__ __forceinline__ void gload16(const void* g, const void* l) {
  __builtin_amdgcn_global_load_lds(
      (const __attribute__((address_space(1))) unsigned int*)(unsigned long long)g,
      (__attribute__((address_space(3))) unsigned int*)(unsigned int)(unsigned long long)l,
      16, 0, 0);
}

// ---------------- conversions ----------------

__global__ __launch_bounds__(256) void convert_x_kernel(
    const float* __restrict__ in, unsigned short* __restrict__ out) {
  int i = (blockIdx.x * 256 + threadIdx.x) * 8;
  float4 a = *(const float4*)(in + i);
  float4 b = *(const float4*)(in + i + 4);
  ushort8 o;
  o[0] = f2bf(a.x); o[1] = f2bf(a.y); o[2] = f2bf(a.z); o[3] = f2bf(a.w);
  o[4] = f2bf(b.x); o[5] = f2bf(b.y); o[6] = f2bf(b.z); o[7] = f2bf(b.w);
  *(ushort8*)(out + i) = o;
}

// [M][N] fp32 -> [N][M] bf16, per-expert (blockIdx.z), 64x64 tiles
__global__ __launch_bounds__(256) void transpose_bf16_kernel(
    const float* __restrict__ in, unsigned short* __restrict__ out, int M, int N) {
  in  += (size_t)blockIdx.z * M * N;
  out += (size_t)blockIdx.z * M * N;
  __shared__ unsigned short t[64][72];
  int tid = threadIdx.x;
  int r0 = blockIdx.y * 64, c0 = blockIdx.x * 64;
#pragma unroll
  for (int rr = 0; rr < 4; rr++) {
    int row = rr * 16 + (tid >> 4);
    int col = (tid & 15) * 4;
    float4 v = *(const float4*)(in + (size_t)(r0 + row) * N + c0 + col);
    t[col + 0][row] = f2bf(v.x);
    t[col + 1][row] = f2bf(v.y);
    t[col + 2][row] = f2bf(v.z);
    t[col + 3][row] = f2bf(v.w);
  }
  __syncthreads();
#pragma unroll
  for (int rr = 0; rr < 2; rr++) {
    int c = rr * 32 + (tid >> 3);
    int m0 = (tid & 7) * 8;
    ushort8 v = *(const ushort8*)&t[c][m0];
    *(ushort8*)(out + (size_t)(c0 + c) * M + r0 + m0) = v;
  }
}

// ---------------- router ----------------

__global__ __launch_bounds__(256) void router_kernel(
    const float* __restrict__ x, const float* __restrict__ wg,
    int* __restrict__ sel_e, float* __restrict__ sel_w, int* __restrict__ counts) {
  int lane = threadIdx.x & 63;
  int t = blockIdx.x * 4 + (threadIdx.x >> 6);
  const float* xr = x + (size_t)t * HDIM;
  float acc[8] = {0, 0, 0, 0, 0, 0, 0, 0};
  for (int i = 0; i < HDIM / 64; i++) {
    int h = i * 64 + lane;
    float xv = xr[h];
    float4 w0 = *(const float4*)(wg + h * 8);
    float4 w1 = *(const float4*)(wg + h * 8 + 4);
    acc[0] += xv * w0.x; acc[1] += xv * w0.y; acc[2] += xv * w0.z; acc[3] += xv * w0.w;
    acc[4] += xv * w1.x; acc[5] += xv * w1.y; acc[6] += xv * w1.z; acc[7] += xv * w1.w;
  }
#pragma unroll
  for (int off = 32; off > 0; off >>= 1) {
#pragma unroll
    for (int e = 0; e < 8; e++) acc[e] += __shfl_xor(acc[e], off, 64);
  }
  if (lane == 0) {
    int e0 = 0; float b0 = acc[0];
#pragma unroll
    for (int e = 1; e < 8; e++) if (acc[e] > b0) { b0 = acc[e]; e0 = e; }
    int e1 = -1; float b1 = -3.4e38f;
#pragma unroll
    for (int e = 0; e < 8; e++) if (e != e0 && acc[e] > b1) { b1 = acc[e]; e1 = e; }
    float q = expf(b1 - b0);                 // softmax denominator cancels in renorm
    float w0 = 1.0f / (1.0f + q);
    float w1 = q / (1.0f + q);
    sel_e[t * 2] = e0; sel_e[t * 2 + 1] = e1;
    sel_w[t * 2] = w0; sel_w[t * 2 + 1] = w1;
    atomicAdd(&counts[e0], 1);
    atomicAdd(&counts[e1], 1);
  }
}

__global__ void offsets_kernel(const int* __restrict__ counts,
                               int* __restrict__ offsets, int* __restrict__ cursor) {
  if (threadIdx.x == 0 && blockIdx.x == 0) {
    int s = 0;
    for (int e = 0; e < NEXP; e++) { offsets[e] = s; cursor[e] = s; s += counts[e]; }
  }
}

__global__ __launch_bounds__(256) void scatter_kernel(
    const int* __restrict__ sel_e, const float* __restrict__ sel_w,
    int* __restrict__ cursor, int* __restrict__ pair_token, float* __restrict__ pair_w) {
  int t = blockIdx.x * 256 + threadIdx.x;
#pragma unroll
  for (int j = 0; j < 2; j++) {
    int e = sel_e[t * 2 + j];
    int pos = atomicAdd(&cursor[e], 1);
    pair_token[pos] = t;
    pair_w[pos] = sel_w[t * 2 + j];
  }
}

// ---------------- expert GEMMs: 256x256 tile, BK=32, 3-slot LDS ring ----------------
// 8 waves (2M x 4N), wave tile 128x64, acc[8][4] f32x4. Per K-tile: 2 phases x
// {ds_read frags | stage 2 gload16 of tile t+2 -> barrier -> setprio(1) 16 MFMA}.
// Counted vmcnt(4) at tile boundary only (tile t+1's 4 staging ops in flight).
// LDS chunk (row, s) holds global k-chunk s ^ ((row>>1)&3)  -> conflict-free reads.
template <int KD, int KSPL, bool GATHER, bool SQRELU>
__global__ __launch_bounds__(512, 2) void moe_gemm_kernel(
    const unsigned short* __restrict__ A0, const unsigned short* __restrict__ B0,
    const int* __restrict__ offsets, const int* __restrict__ counts,
    const int* __restrict__ pair_token, const float* __restrict__ pair_w,
    unsigned short* __restrict__ h1out, float* __restrict__ out) {
  constexpr int ND = SQRELU ? FFDIM : HDIM;
  constexpr int KLEN = KD / KSPL;
  constexpr int NTILES = KLEN / 32;

  int e  = blockIdx.z / KSPL;
  int ks = blockIdx.z % KSPL;
  int segstart = offsets[e];
  int segcnt = counts[e];
  int by = blockIdx.y;
  if (by * 256 >= segcnt) return;
  int bx = blockIdx.x;
  const unsigned short* B = B0 + (size_t)e * ND * KD + (size_t)ks * KLEN;
  const unsigned short* Abase = A0 + (size_t)ks * KLEN;

  int tid = threadIdx.x;
  int lane = tid & 63;
  int wv = tid >> 6;       // 0..7
  int wr = wv >> 2;        // 0..1  (M)
  int wc = wv & 3;         // 0..3  (N)
  int g  = lane >> 4;      // 0..3
  int lr = lane & 15;

  // staging source pointers (pre-swizzled k-chunk so LDS layout is swizzled)
  int kbElem = (((tid & 3) ^ ((tid >> 3) & 3))) * 8;
  const unsigned short* aP[2];
  const unsigned short* bP[2];
#pragma unroll
  for (int r = 0; r < 2; r++) {
    int arow = r * 128 + (tid >> 2);
    int idx = by * 256 + arow;
    if (idx >= segcnt) idx = segcnt - 1;   // clamp pad rows
    int p = segstart + idx;
    size_t rowoff;
    if (GATHER) rowoff = (size_t)pair_token[p] * KD;
    else        rowoff = (size_t)p * KD;
    aP[r] = Abase + rowoff + kbElem;
    int n = bx * 256 + arow;
    bP[r] = B + (size_t)n * KD + kbElem;
  }

  __shared__ char lds[98304];              // 3 slots x (A 16KB + B 16KB)
  const char* ldsc = lds;
  int ldsStage = wv * 1024;                // wave-uniform lane base (lane*16 added by HW)

  // per-thread LDS read bases (within a slot)
  int swz = (g ^ ((lr >> 1) & 3)) * 16;
  int abase = (wr * 128 + lr) * 64 + swz;             // + mi*1024
  int bbase = 16384 + (wc * 64 + lr) * 64 + swz;      // + nj*1024

  f32x4 acc[8][4];
#pragma unroll
  for (int i = 0; i < 8; i++)
#pragma unroll
    for (int j = 0; j < 4; j++) acc[i][j] = (f32x4){0.f, 0.f, 0.f, 0.f};

  // prologue: stage tiles 0 and 1
#pragma unroll
  for (int t = 0; t < 2; t++) {
    int so = t * 32768;
#pragma unroll
    for (int r = 0; r < 2; r++) gload16(aP[r], ldsc + so + r * 8192 + ldsStage);
#pragma unroll
    for (int r = 0; r < 2; r++) gload16(bP[r], ldsc + so + 16384 + r * 8192 + ldsStage);
#pragma unroll
    for (int r = 0; r < 2; r++) { aP[r] += 32; bP[r] += 32; }
  }

  int rsOff = 0, rs2Off = 65536;
  for (int t = 0; t < NTILES; ++t) {
    asm volatile("s_waitcnt vmcnt(4)" ::: "memory");  // tile t landed; t+1 in flight
    __builtin_amdgcn_s_barrier();
    __builtin_amdgcn_sched_barrier(0);
    bool doStage = (t + 2 < NTILES);

    // ---- phase 0: A frags (all mi) + B frags nj 0..1 ----
    short8 af[8], bf[2], bf2[2];
#pragma unroll
    for (int mi = 0; mi < 8; mi++)
      af[mi] = *(const short8*)(ldsc + rsOff + abase + mi * 1024);
#pragma unroll
    for (int j = 0; j < 2; j++)
      bf[j] = *(const short8*)(ldsc + rsOff + bbase + j * 1024);
    if (doStage) {
      gload16(aP[0], ldsc + rs2Off + ldsStage);
      gload16(aP[1], ldsc + rs2Off + 8192 + ldsStage);
    }
    __builtin_amdgcn_s_barrier();
    __builtin_amdgcn_s_setprio(1);
#pragma unroll
    for (int mi = 0; mi < 8; mi++)
#pragma unroll
      for (int j = 0; j < 2; j++)
        acc[mi][j] = __builtin_amdgcn_mfma_f32_16x16x32_bf16(af[mi], bf[j], acc[mi][j], 0, 0, 0);
    __builtin_amdgcn_s_setprio(0);
    __builtin_amdgcn_s_barrier();

    // ---- phase 1: B frags nj 2..3 ----
#pragma unroll
    for (int j = 0; j < 2; j++)
      bf2[j] = *(const short8*)(ldsc + rsOff + bbase + (2 + j) * 1024);
    if (doStage) {
      gload16(bP[0], ldsc + rs2Off + 16384 + ldsStage);
      gload16(bP[1], ldsc + rs2Off + 16384 + 8192 + ldsStage);
#pragma unroll
      for (int r = 0; r < 2; r++) { aP[r] += 32; bP[r] += 32; }
    }
    __builtin_amdgcn_s_barrier();
    __builtin_amdgcn_s_setprio(1);
#pragma unroll
    for (int mi = 0; mi < 8; mi++)
#pragma unroll
      for (int j = 0; j < 2; j++)
        acc[mi][2 + j] = __builtin_amdgcn_mfma_f32_16x16x32_bf16(af[mi], bf2[j], acc[mi][2 + j], 0, 0, 0);
    __builtin_amdgcn_s_setprio(0);

    rsOff  = (rsOff  == 65536) ? 0 : rsOff  + 32768;
    rs2Off = (rs2Off == 65536) ? 0 : rs2Off + 32768;
  }

  // ---- epilogue: C/D layout col=lane&15, row=(lane>>4)*4+q ----
  int colb = bx * 256 + wc * 64 + lr;      // + nj*16
  int rowb = by * 256 + wr * 128 + g * 4;  // + mi*16 + q
#pragma unroll
  for (int mi = 0; mi < 8; mi++) {
#pragma unroll
    for (int q = 0; q < 4; q++) {
      int idx = rowb + mi * 16 + q;
      if (idx < segcnt) {
        int p = segstart + idx;
        if (SQRELU) {
          size_t ro = (size_t)p * FFDIM + colb;
#pragma unroll
          for (int j = 0; j < 4; j++) {
            float v = acc[mi][j][q];
            v = v > 0.f ? v * v : 0.f;
            h1out[ro + j * 16] = f2bf(v);
          }
        } else {
          int tok = pair_token[p];
          float wgt = pair_w[p];
          size_t ro = (size_t)tok * HDIM + colb;
#pragma unroll
          for (int j = 0; j < 4; j++)
            atomicAdd(out + ro + j * 16, acc[mi][j][q] * wgt);
        }
      }
    }
  }
}

// ---------------- launch ----------------

extern "C" void kernel_launch(void* const* d_in, const int* in_sizes, int n_in,
                              void* d_out, int out_size, void* d_ws, size_t ws_size,
                              hipStream_t stream) {
  (void)in_sizes; (void)n_in; (void)out_size; (void)ws_size;
  const float* x     = (const float*)d_in[0];
  const float* Wg    = (const float*)d_in[1];
  const float* Wfc   = (const float*)d_in[2];
  const float* Wproj = (const float*)d_in[3];
  float* out = (float*)d_out;

  char* w = (char*)d_ws;
  size_t o = 0;
  auto take = [&](size_t n) { char* p = w + o; o += (n + 255) & ~(size_t)255; return p; };
  unsigned short* xb     = (unsigned short*)take((size_t)T_TOK * HDIM * 2);
  unsigned short* WfcT   = (unsigned short*)take((size_t)NEXP * FFDIM * HDIM * 2);
  unsigned short* WprojT = (unsigned short*)take((size_t)NEXP * HDIM * FFDIM * 2);
  unsigned short* h1     = (unsigned short*)take((size_t)NPAIR * FFDIM * 2);
  int*   sel_e      = (int*)take(T_TOK * 2 * 4);
  float* sel_w      = (float*)take(T_TOK * 2 * 4);
  int*   pair_token = (int*)take(NPAIR * 4);
  float* pair_w     = (float*)take(NPAIR * 4);
  int*   counts     = (int*)take(3 * 8 * 4);
  int*   offsets    = counts + 8;
  int*   cursor     = counts + 16;

  hipMemsetAsync(out, 0, (size_t)T_TOK * HDIM * 4, stream);
  hipMemsetAsync(counts, 0, 96, stream);

  convert_x_kernel<<<T_TOK * HDIM / (256 * 8), 256, 0, stream>>>(x, xb);
  transpose_bf16_kernel<<<dim3(FFDIM / 64, HDIM / 64, NEXP), 256, 0, stream>>>(Wfc, WfcT, HDIM, FFDIM);
  transpose_bf16_kernel<<<dim3(HDIM / 64, FFDIM / 64, NEXP), 256, 0, stream>>>(Wproj, WprojT, FFDIM, HDIM);
  router_kernel<<<T_TOK / 4, 256, 0, stream>>>(x, Wg, sel_e, sel_w, counts);
  offsets_kernel<<<1, 64, 0, stream>>>(counts, offsets, cursor);
  scatter_kernel<<<T_TOK / 256, 256, 0, stream>>>(sel_e, sel_w, cursor, pair_token, pair_w);

  // GEMM1: per expert, [seg x 1024] x [1024 x 4096] -> relu^2 -> h1 (bf16)
  moe_gemm_kernel<HDIM, 1, true, true>
      <<<dim3(FFDIM / 256, 32, NEXP), 512, 0, stream>>>(xb, WfcT, offsets, counts,
                                                        pair_token, pair_w, h1, nullptr);
  // GEMM2: per expert, [seg x 4096] x [4096 x 1024] -> weighted atomic combine, split-K=2
  moe_gemm_kernel<FFDIM, 2, false, false>
      <<<dim3(HDIM / 256, 32, NEXP * 2), 512, 0, stream>>>(h1, WprojT, offsets, counts,
                                                           pair_token, pair_w, nullptr, out);
}

// Round 4
// 460.588 us; speedup vs baseline: 1.1815x; 1.0442x over previous
//
#include <hip/hip_runtime.h>

#define T_TOK 4096
#define HDIM  1024
#define NEXP  8
#define FFDIM 4096
#define NPAIR 8192   // T_TOK * topk

typedef __attribute__((ext_vector_type(8))) short short8;
typedef __attribute__((ext_vector_type(8))) unsigned short ushort8;
typedef __attribute__((ext_vector_type(4))) float f32x4;

__device__ __forceinline__ unsigned short f2bf(float f) {
  unsigned int u = __float_as_uint(f);
  u += 0x7fffu + ((u >> 16) & 1u);   // RNE
  return (unsigned short)(u >> 16);
}

// global -> LDS direct copy, 16B per lane. LDS dest is wave-uniform base;
// HW writes lane l at base + l*16.
__device__ __forceinline__ void gload16(const void* g, const void* l) {
  __builtin_amdgcn_global_load_lds(
      (const __attribute__((address_space(1))) unsigned int*)(unsigned long long)g,
      (__attribute__((address_space(3))) unsigned int*)(unsigned int)(unsigned long long)l,
      16, 0, 0);
}

// ---------------- conversions ----------------

__global__ __launch_bounds__(256) void convert_x_kernel(
    const float* __restrict__ in, unsigned short* __restrict__ out) {
  int i = (blockIdx.x * 256 + threadIdx.x) * 8;
  float4 a = *(const float4*)(in + i);
  float4 b = *(const float4*)(in + i + 4);
  ushort8 o;
  o[0] = f2bf(a.x); o[1] = f2bf(a.y); o[2] = f2bf(a.z); o[3] = f2bf(a.w);
  o[4] = f2bf(b.x); o[5] = f2bf(b.y); o[6] = f2bf(b.z); o[7] = f2bf(b.w);
  *(ushort8*)(out + i) = o;
}

// [M][N] fp32 -> [N][M] bf16, per-expert (blockIdx.z), 64x64 tiles
__global__ __launch_bounds__(256) void transpose_bf16_kernel(
    const float* __restrict__ in, unsigned short* __restrict__ out, int M, int N) {
  in  += (size_t)blockIdx.z * M * N;
  out += (size_t)blockIdx.z * M * N;
  __shared__ unsigned short t[64][72];
  int tid = threadIdx.x;
  int r0 = blockIdx.y * 64, c0 = blockIdx.x * 64;
#pragma unroll
  for (int rr = 0; rr < 4; rr++) {
    int row = rr * 16 + (tid >> 4);
    int col = (tid & 15) * 4;
    float4 v = *(const float4*)(in + (size_t)(r0 + row) * N + c0 + col);
    t[col + 0][row] = f2bf(v.x);
    t[col + 1][row] = f2bf(v.y);
    t[col + 2][row] = f2bf(v.z);
    t[col + 3][row] = f2bf(v.w);
  }
  __syncthreads();
#pragma unroll
  for (int rr = 0; rr < 2; rr++) {
    int c = rr * 32 + (tid >> 3);
    int m0 = (tid & 7) * 8;
    ushort8 v = *(const ushort8*)&t[c][m0];
    *(ushort8*)(out + (size_t)(c0 + c) * M + r0 + m0) = v;
  }
}

// ---------------- router ----------------

__global__ __launch_bounds__(256) void router_kernel(
    const float* __restrict__ x, const float* __restrict__ wg,
    int* __restrict__ sel_e, float* __restrict__ sel_w, int* __restrict__ counts) {
  int lane = threadIdx.x & 63;
  int t = blockIdx.x * 4 + (threadIdx.x >> 6);
  const float* xr = x + (size_t)t * HDIM;
  float acc[8] = {0, 0, 0, 0, 0, 0, 0, 0};
  for (int i = 0; i < HDIM / 64; i++) {
    int h = i * 64 + lane;
    float xv = xr[h];
    float4 w0 = *(const float4*)(wg + h * 8);
    float4 w1 = *(const float4*)(wg + h * 8 + 4);
    acc[0] += xv * w0.x; acc[1] += xv * w0.y; acc[2] += xv * w0.z; acc[3] += xv * w0.w;
    acc[4] += xv * w1.x; acc[5] += xv * w1.y; acc[6] += xv * w1.z; acc[7] += xv * w1.w;
  }
#pragma unroll
  for (int off = 32; off > 0; off >>= 1) {
#pragma unroll
    for (int e = 0; e < 8; e++) acc[e] += __shfl_xor(acc[e], off, 64);
  }
  if (lane == 0) {
    int e0 = 0; float b0 = acc[0];
#pragma unroll
    for (int e = 1; e < 8; e++) if (acc[e] > b0) { b0 = acc[e]; e0 = e; }
    int e1 = -1; float b1 = -3.4e38f;
#pragma unroll
    for (int e = 0; e < 8; e++) if (e != e0 && acc[e] > b1) { b1 = acc[e]; e1 = e; }
    float q = expf(b1 - b0);                 // softmax denominator cancels in renorm
    float w0 = 1.0f / (1.0f + q);
    float w1 = q / (1.0f + q);
    sel_e[t * 2] = e0; sel_e[t * 2 + 1] = e1;
    sel_w[t * 2] = w0; sel_w[t * 2 + 1] = w1;
    atomicAdd(&counts[e0], 1);
    atomicAdd(&counts[e1], 1);
  }
}

__global__ void offsets_kernel(const int* __restrict__ counts,
                               int* __restrict__ offsets, int* __restrict__ cursor) {
  if (threadIdx.x == 0 && blockIdx.x == 0) {
    int s = 0;
    for (int e = 0; e < NEXP; e++) { offsets[e] = s; cursor[e] = s; s += counts[e]; }
  }
}

__global__ __launch_bounds__(256) void scatter_kernel(
    const int* __restrict__ sel_e, const float* __restrict__ sel_w,
    int* __restrict__ cursor, int* __restrict__ pair_token, float* __restrict__ pair_w) {
  int t = blockIdx.x * 256 + threadIdx.x;
#pragma unroll
  for (int j = 0; j < 2; j++) {
    int e = sel_e[t * 2 + j];
    int pos = atomicAdd(&cursor[e], 1);
    pair_token[pos] = t;
    pair_w[pos] = sel_w[t * 2 + j];
  }
}

// -------- expert GEMMs: 128x128 tile, BK=32, 3-slot LDS ring, 3 blocks/CU --------
// 4 waves (2M x 2N), wave tile 64x64, acc[4][4]. Per K-tile: 2 phases x
// {ds_read frags | stage gload16 of tile t+2 -> barrier -> setprio(1) 8 MFMA}.
// Counted vmcnt(4) at tile top (tile t+1's 4 ops in flight). FINAL iteration
// must drain vmcnt(0): nothing else is in flight there, so vmcnt(4) would be
// a no-op and the last tile would be read before landing (round-3 race).
// LDS slot 16KB (A 8K + B 8K), 3 slots = 48KB -> 3 blocks/CU of latency cover.
// Swizzle: LDS chunk(row, c) holds global k-chunk c ^ (row&3); conflict-free.
template <int KD, int KSPL, bool GATHER, bool SQRELU>
__global__ __launch_bounds__(256, 3) void moe_gemm_kernel(
    const unsigned short* __restrict__ A0, const unsigned short* __restrict__ B0,
    const int* __restrict__ offsets, const int* __restrict__ counts,
    const int* __restrict__ pair_token, const float* __restrict__ pair_w,
    unsigned short* __restrict__ h1out, float* __restrict__ out) {
  constexpr int ND = SQRELU ? FFDIM : HDIM;
  constexpr int KLEN = KD / KSPL;
  constexpr int NTILES = KLEN / 32;

  int e  = blockIdx.z / KSPL;
  int ks = blockIdx.z % KSPL;
  int segstart = offsets[e];
  int segcnt = counts[e];
  int by = blockIdx.y;
  if (by * 128 >= segcnt) return;
  int bx = blockIdx.x;
  const unsigned short* B = B0 + (size_t)e * ND * KD + (size_t)ks * KLEN;
  const unsigned short* Abase = A0 + (size_t)ks * KLEN;

  int tid = threadIdx.x;
  int lane = tid & 63;
  int wv = tid >> 6;       // 0..3
  int wr = wv >> 1;        // 0..1  (M)
  int wc = wv & 1;         // 0..1  (N)
  int g  = lane >> 4;      // 0..3
  int lr = lane & 15;

  // staging source pointers; k-chunk pre-swizzled so LDS layout is swizzled
  int kbElem = ((tid & 3) ^ ((tid >> 2) & 3)) * 8;
  const unsigned short* aP[2];
  const unsigned short* bP[2];
#pragma unroll
  for (int r = 0; r < 2; r++) {
    int arow = r * 64 + (tid >> 2);
    int idx = by * 128 + arow;
    if (idx >= segcnt) idx = segcnt - 1;   // clamp pad rows
    int p = segstart + idx;
    size_t rowoff;
    if (GATHER) rowoff = (size_t)pair_token[p] * KD;
    else        rowoff = (size_t)p * KD;
    aP[r] = Abase + rowoff + kbElem;
    int n = bx * 128 + arow;
    bP[r] = B + (size_t)n * KD + kbElem;
  }

  __shared__ char lds[49152];              // 3 slots x (A 8KB + B 8KB)
  const char* ldsc = lds;
  int ldsStage = wv * 1024;                // wave-uniform base (lane*16 added by HW)

  // per-thread LDS read bases (within a slot)
  int swz = (g ^ (lr & 3)) * 16;
  int abase0 = (wr * 64 + lr) * 64 + swz;            // + mi*1024
  int bbase0 = 8192 + (wc * 64 + lr) * 64 + swz;     // + nj*1024

  f32x4 acc[4][4];
#pragma unroll
  for (int i = 0; i < 4; i++)
#pragma unroll
    for (int j = 0; j < 4; j++) acc[i][j] = (f32x4){0.f, 0.f, 0.f, 0.f};

  // prologue: stage tiles 0 and 1 into slots 0,1
#pragma unroll
  for (int t = 0; t < 2; t++) {
    int so = t * 16384;
#pragma unroll
    for (int r = 0; r < 2; r++) gload16(aP[r], ldsc + so + r * 4096 + ldsStage);
#pragma unroll
    for (int r = 0; r < 2; r++) gload16(bP[r], ldsc + so + 8192 + r * 4096 + ldsStage);
#pragma unroll
    for (int r = 0; r < 2; r++) { aP[r] += 32; bP[r] += 32; }
  }

  int rsOff = 0, rs2Off = 32768;
  for (int t = 0; t < NTILES; ++t) {
    // tile t landed; t+1 (if any) stays in flight. Last iter: drain fully.
    if (t < NTILES - 1) {
      asm volatile("s_waitcnt vmcnt(4)" ::: "memory");
    } else {
      asm volatile("s_waitcnt vmcnt(0)" ::: "memory");
    }
    __builtin_amdgcn_s_barrier();
    __builtin_amdgcn_sched_barrier(0);
    bool doStage = (t + 2 < NTILES);

    // ---- phase 0: A frags (all mi) + B frags nj 0..1; stage A of t+2 ----
    short8 af[4], bf[2], bf2[2];
#pragma unroll
    for (int mi = 0; mi < 4; mi++)
      af[mi] = *(const short8*)(ldsc + rsOff + abase0 + mi * 1024);
#pragma unroll
    for (int j = 0; j < 2; j++)
      bf[j] = *(const short8*)(ldsc + rsOff + bbase0 + j * 1024);
    if (doStage) {
      gload16(aP[0], ldsc + rs2Off + ldsStage);
      gload16(aP[1], ldsc + rs2Off + 4096 + ldsStage);
    }
    __builtin_amdgcn_s_barrier();
    __builtin_amdgcn_s_setprio(1);
#pragma unroll
    for (int mi = 0; mi < 4; mi++)
#pragma unroll
      for (int j = 0; j < 2; j++)
        acc[mi][j] = __builtin_amdgcn_mfma_f32_16x16x32_bf16(af[mi], bf[j], acc[mi][j], 0, 0, 0);
    __builtin_amdgcn_s_setprio(0);
    __builtin_amdgcn_s_barrier();

    // ---- phase 1: B frags nj 2..3; stage B of t+2 ----
#pragma unroll
    for (int j = 0; j < 2; j++)
      bf2[j] = *(const short8*)(ldsc + rsOff + bbase0 + (2 + j) * 1024);
    if (doStage) {
      gload16(bP[0], ldsc + rs2Off + 8192 + ldsStage);
      gload16(bP[1], ldsc + rs2Off + 8192 + 4096 + ldsStage);
#pragma unroll
      for (int r = 0; r < 2; r++) { aP[r] += 32; bP[r] += 32; }
    }
    __builtin_amdgcn_s_barrier();
    __builtin_amdgcn_s_setprio(1);
#pragma unroll
    for (int mi = 0; mi < 4; mi++)
#pragma unroll
      for (int j = 0; j < 2; j++)
        acc[mi][2 + j] = __builtin_amdgcn_mfma_f32_16x16x32_bf16(af[mi], bf2[j], acc[mi][2 + j], 0, 0, 0);
    __builtin_amdgcn_s_setprio(0);

    rsOff  = (rsOff  == 32768) ? 0 : rsOff  + 16384;
    rs2Off = (rs2Off == 32768) ? 0 : rs2Off + 16384;
  }

  // ---- epilogue: C/D layout col=lane&15, row=(lane>>4)*4+q ----
  int colb = bx * 128 + wc * 64 + lr;      // + nj*16
  int rowb = by * 128 + wr * 64 + g * 4;   // + mi*16 + q
#pragma unroll
  for (int mi = 0; mi < 4; mi++) {
#pragma unroll
    for (int q = 0; q < 4; q++) {
      int idx = rowb + mi * 16 + q;
      if (idx < segcnt) {
        int p = segstart + idx;
        if (SQRELU) {
          size_t ro = (size_t)p * FFDIM + colb;
#pragma unroll
          for (int j = 0; j < 4; j++) {
            float v = acc[mi][j][q];
            v = v > 0.f ? v * v : 0.f;
            h1out[ro + j * 16] = f2bf(v);
          }
        } else {
          int tok = pair_token[p];
          float wgt = pair_w[p];
          size_t ro = (size_t)tok * HDIM + colb;
#pragma unroll
          for (int j = 0; j < 4; j++)
            atomicAdd(out + ro + j * 16, acc[mi][j][q] * wgt);
        }
      }
    }
  }
}

// ---------------- launch ----------------

extern "C" void kernel_launch(void* const* d_in, const int* in_sizes, int n_in,
                              void* d_out, int out_size, void* d_ws, size_t ws_size,
                              hipStream_t stream) {
  (void)in_sizes; (void)n_in; (void)out_size; (void)ws_size;
  const float* x     = (const float*)d_in[0];
  const float* Wg    = (const float*)d_in[1];
  const float* Wfc   = (const float*)d_in[2];
  const float* Wproj = (const float*)d_in[3];
  float* out = (float*)d_out;

  char* w = (char*)d_ws;
  size_t o = 0;
  auto take = [&](size_t n) { char* p = w + o; o += (n + 255) & ~(size_t)255; return p; };
  unsigned short* xb     = (unsigned short*)take((size_t)T_TOK * HDIM * 2);
  unsigned short* WfcT   = (unsigned short*)take((size_t)NEXP * FFDIM * HDIM * 2);
  unsigned short* WprojT = (unsigned short*)take((size_t)NEXP * HDIM * FFDIM * 2);
  unsigned short* h1     = (unsigned short*)take((size_t)NPAIR * FFDIM * 2);
  int*   sel_e      = (int*)take(T_TOK * 2 * 4);
  float* sel_w      = (float*)take(T_TOK * 2 * 4);
  int*   pair_token = (int*)take(NPAIR * 4);
  float* pair_w     = (float*)take(NPAIR * 4);
  int*   counts     = (int*)take(3 * 8 * 4);
  int*   offsets    = counts + 8;
  int*   cursor     = counts + 16;

  hipMemsetAsync(out, 0, (size_t)T_TOK * HDIM * 4, stream);
  hipMemsetAsync(counts, 0, 96, stream);

  convert_x_kernel<<<T_TOK * HDIM / (256 * 8), 256, 0, stream>>>(x, xb);
  transpose_bf16_kernel<<<dim3(FFDIM / 64, HDIM / 64, NEXP), 256, 0, stream>>>(Wfc, WfcT, HDIM, FFDIM);
  transpose_bf16_kernel<<<dim3(HDIM / 64, FFDIM / 64, NEXP), 256, 0, stream>>>(Wproj, WprojT, FFDIM, HDIM);
  router_kernel<<<T_TOK / 4, 256, 0, stream>>>(x, Wg, sel_e, sel_w, counts);
  offsets_kernel<<<1, 64, 0, stream>>>(counts, offsets, cursor);
  scatter_kernel<<<T_TOK / 256, 256, 0, stream>>>(sel_e, sel_w, cursor, pair_token, pair_w);

  // GEMM1: per expert, [seg x 1024] x [1024 x 4096] -> relu^2 -> h1 (bf16)
  moe_gemm_kernel<HDIM, 1, true, true>
      <<<dim3(FFDIM / 128, 64, NEXP), 256, 0, stream>>>(xb, WfcT, offsets, counts,
                                                        pair_token, pair_w, h1, nullptr);
  // GEMM2: per expert, [seg x 4096] x [4096 x 1024] -> weighted atomic combine, split-K=2
  moe_gemm_kernel<FFDIM, 2, false, false>
      <<<dim3(HDIM / 128, 64, NEXP * 2), 256, 0, stream>>>(h1, WprojT, offsets, counts,
                                                           pair_token, pair_w, nullptr, out);
}